// Round 14
// baseline (383.799 us; speedup 1.0000x reference)
//
#include <hip/hip_runtime.h>
#include <stdint.h>

typedef unsigned long long u64;
typedef unsigned short u16;
typedef __attribute__((ext_vector_type(8))) short short8;
typedef __attribute__((ext_vector_type(4))) float f32x4;

// Problem constants
#define NB   16
#define NT   12
#define BTc  192     // NB*NT
#define NN   4096
#define DD   64
#define MM   128
#define TOPK 32
#define KTH  36      // threshold = 36th-largest thread-max (>=36 elems >= T)
#define CAP  128     // candidate capacity (E[c]~54, P(c>128) ~ 7 sigma)

// d_out float offsets (outputs concatenated flat)
#define SEL1_OFF 0ULL
#define SEL2_OFF 50331648ULL
#define BIDX_OFF 100663296ULL
#define TIDX_OFF 101449728ULL
#define IDX_OFF  102236160ULL
// bf16 logits scratch (201.3 MB) occupies exactly the SEL1 region; row r's
// logits are consumed by row r's block before it writes sel1 row r. [proven]

__device__ __forceinline__ unsigned ord32(float f) {
    unsigned u = __float_as_uint(f);
    return (u & 0x80000000u) ? ~u : (u | 0x80000000u);
}
__device__ __forceinline__ u16 f2bf(float f) {   // RNE round to bf16
    unsigned u = __float_as_uint(f);
    unsigned r = u + 0x7FFFu + ((u >> 16) & 1u);
    return (u16)(r >> 16);
}
__device__ __forceinline__ float bf2f(short s) {
    return __uint_as_float(((unsigned)(u16)s) << 16);
}
__device__ __forceinline__ u64 pack4bf(float4 v) {
    return (u64)f2bf(v.x) | ((u64)f2bf(v.y) << 16) |
           ((u64)f2bf(v.z) << 32) | ((u64)f2bf(v.w) << 48);
}
// descending bitonic sort across 64 lanes (f32)
__device__ __forceinline__ float sort64f_desc(float v, int l) {
#pragma unroll
    for (int k = 2; k <= 64; k <<= 1) {
#pragma unroll
        for (int j = k >> 1; j >= 1; j >>= 1) {
            float o = __shfl_xor(v, j);
            bool takeMax = (((l & j) == 0) == ((l & k) == 0));
            v = takeMax ? fmaxf(v, o) : fminf(v, o);
        }
    }
    return v;
}
// merge two desc-sorted 64-lane arrays -> desc-sorted top-64 of the union
__device__ __forceinline__ float merge64f_desc(float a, float b, int l) {
    float rb = __shfl_xor(b, 63);
    float v = fmaxf(a, rb);
#pragma unroll
    for (int j = 32; j >= 1; j >>= 1) {
        float o = __shfl_xor(v, j);
        v = ((l & j) == 0) ? fmaxf(v, o) : fminf(v, o);
    }
    return v;
}
// descending bitonic sort across 64 lanes (u64 keys)
__device__ __forceinline__ u64 sort64_desc(u64 v, int l) {
#pragma unroll
    for (int k = 2; k <= 64; k <<= 1) {
#pragma unroll
        for (int j = k >> 1; j >= 1; j >>= 1) {
            u64 o = __shfl_xor(v, j);
            bool takeMax = (((l & j) == 0) == ((l & k) == 0));
            v = takeMax ? (v > o ? v : o) : (v < o ? v : o);
        }
    }
    return v;
}

// ---------------------------------------------------------------------------
// K1: approx logits via bf16 MFMA; C staged through LDS for coalesced stores
// (R13-proven, ~111 us).
// ---------------------------------------------------------------------------
__global__ __launch_bounds__(256) void k1_logits_bf16(const float* __restrict__ nv1,
                                                      const float* __restrict__ nv2,
                                                      const float* __restrict__ emb,
                                                      u16* __restrict__ logitsB) {
    __shared__ u16 S[2 * 128 * 128];     // 64 KB: A tile | B tile; reused for C
    u16* Als = S;                        // [m][k] swizzled
    u16* Bls = S + 128 * 128;            // [n][k] swizzled (B^T layout)

    const int tid = threadIdx.x;
    const int nt  = blockIdx.x;      // 0..31
    const int bt  = blockIdx.y;      // 0..191
    const int n0  = nt * 128;

#pragma unroll
    for (int it = 0; it < 16; ++it) {
        int f4  = it * 256 + tid;
        int row = f4 >> 5;           // m
        int kq  = f4 & 31;
        float4 a = *(const float4*)(emb + row * 128 + kq * 4);
        int byte = row * 256 + ((kq * 8) ^ ((row & 7) << 4));
        *(u64*)((char*)Als + byte) = pack4bf(a);
    }
#pragma unroll
    for (int it = 0; it < 16; ++it) {
        int f4  = it * 256 + tid;
        int row = f4 >> 5;           // n within tile
        int kq  = f4 & 31;
        const float* src = (kq < 16)
            ? (nv1 + ((size_t)bt * NN + n0 + row) * DD + kq * 4)
            : (nv2 + ((size_t)bt * NN + n0 + row) * DD + (kq - 16) * 4);
        float4 bv = *(const float4*)src;
        int byte = row * 256 + ((kq * 8) ^ ((row & 7) << 4));
        *(u64*)((char*)Bls + byte) = pack4bf(bv);
    }
    __syncthreads();

    const int w  = tid >> 6;
    const int l  = tid & 63;
    const int mb = (w >> 1) * 64;
    const int nb = (w & 1) * 64;
    const int xr = (l & 7) << 4;

    f32x4 acc[4][4];
#pragma unroll
    for (int mi = 0; mi < 4; ++mi)
#pragma unroll
        for (int ni = 0; ni < 4; ++ni) acc[mi][ni] = {0.f, 0.f, 0.f, 0.f};

#pragma unroll
    for (int ks = 0; ks < 4; ++ks) {
        const int kb = (ks * 64 + (l >> 4) * 16) ^ xr;
        short8 a[4], b[4];
#pragma unroll
        for (int mi = 0; mi < 4; ++mi) {
            int row = mb + mi * 16 + (l & 15);
            a[mi] = *(const short8*)((const char*)Als + row * 256 + kb);
        }
#pragma unroll
        for (int ni = 0; ni < 4; ++ni) {
            int row = nb + ni * 16 + (l & 15);
            b[ni] = *(const short8*)((const char*)Bls + row * 256 + kb);
        }
#pragma unroll
        for (int mi = 0; mi < 4; ++mi)
#pragma unroll
            for (int ni = 0; ni < 4; ++ni)
                acc[mi][ni] = __builtin_amdgcn_mfma_f32_16x16x32_bf16(
                    a[mi], b[ni], acc[mi][ni], 0, 0, 0);
    }

    // ---- C staging: reuse S for the 128x128 bf16 C tile (swizzled) ----
    __syncthreads();
#pragma unroll
    for (int mi = 0; mi < 4; ++mi) {
#pragma unroll
        for (int ni = 0; ni < 4; ++ni) {
#pragma unroll
            for (int r = 0; r < 4; ++r) {
                int m   = mb + mi * 16 + (l >> 4) * 4 + r;
                int col = nb + ni * 16 + (l & 15);
                int byte = m * 256 + ((col * 2) ^ (((m >> 2) & 3) << 5));
                *(u16*)((char*)S + byte) = f2bf(acc[mi][ni][r]);
            }
        }
    }
    __syncthreads();

    const size_t rbase = (size_t)bt * MM * NN;
#pragma unroll
    for (int it = 0; it < 8; ++it) {
        int f    = it * 256 + tid;   // 0..2047
        int m    = f >> 4;           // 0..127
        int ck   = f & 15;           // 16B chunk within row
        int byte = m * 256 + ((ck * 16) ^ (((m >> 2) & 3) << 5));
        f32x4 v  = *(const f32x4*)((const char*)S + byte);
        *(f32x4*)(logitsB + rbase + (size_t)m * NN + n0 + ck * 8) = v;
    }
}

// ---------------------------------------------------------------------------
// K2 (fused, v10): ONE BLOCK (4 waves, 256 threads) PER ROW — divides the
// per-row serial pipeline ~4x vs the one-wave-per-row structure:
//  1. scan: thread t holds elems [16t,16t+16); per-wave sort64 of thread-maxima
//     -> LDS -> wave 0 merges (3x bitonic merge) -> T = 36th-largest of 256
//     thread-maxima (>=36 elements >= T, same guarantee as proven KTH=36)
//  2. compact: 16 ballot-iters/thread, cross-wave bases via LDS atomicAdd
//     (candidate order arbitrary — keys carry (value,index))
//  3. dots: candidate i -> wave i&3, lane i>>2; exact seq-fmaf fp32 (verbatim
//     proven order) -> keyL[i]
//  4. wave 0: sort128 (2x sort64 + merge) -> top-32 desc; writes idx/b/t/widx
//  5. all 4 waves: winner gather (8 winners/iter, 256B contiguous per half-row)
// Grid 24576 blocks, XCD-swizzled (bijective 8x3072; 128-row bt chunks/XCD).
// ---------------------------------------------------------------------------
__global__ __launch_bounds__(256) void k2_fused(const u16* logitsB,
                                                const float* __restrict__ nv1,
                                                const float* __restrict__ nv2,
                                                const float* __restrict__ emb,
                                                float* out) {
    const int tid = threadIdx.x;
    const int l   = tid & 63;
    const int w   = tid >> 6;
    const int bid = (int)blockIdx.x;
    const int row = (bid & 7) * 3072 + (bid >> 3);   // 0..24575
    const int bt  = row >> 7;
    const int m   = row & 127;
    const u16* src = logitsB + (size_t)row * NN;

    __shared__ float sortedW[4][64];
    __shared__ float embrow[128];
    __shared__ int   cand[CAP];
    __shared__ u64   keyL[CAP];
    __shared__ int   widx[TOPK];
    __shared__ int   cnt;
    __shared__ float Tsh;

    if (tid < 128) embrow[tid] = emb[m * 128 + tid];
    if (tid < CAP) keyL[tid] = 0ull;
    if (tid == 0)  cnt = 0;

    // ---- 1. scan: 32B per thread, thread-max over 16 elems ----
    const short8 c0 = *(const short8*)(src + tid * 16);
    const short8 c1 = *(const short8*)(src + tid * 16 + 8);
    float tmax = -INFINITY;
#pragma unroll
    for (int e = 0; e < 8; ++e) tmax = fmaxf(tmax, bf2f(c0[e]));
#pragma unroll
    for (int e = 0; e < 8; ++e) tmax = fmaxf(tmax, bf2f(c1[e]));

    sortedW[w][l] = sort64f_desc(tmax, l);
    __syncthreads();

    if (w == 0) {
        float m01 = merge64f_desc(sortedW[0][l], sortedW[1][l], l);
        float m23 = merge64f_desc(sortedW[2][l], sortedW[3][l], l);
        float top = merge64f_desc(m01, m23, l);    // top-64 of 256, desc
        if (l == KTH - 1) Tsh = top;               // 36th largest
    }
    __syncthreads();
    const float T = Tsh;

    // ---- 2. compact: 16 iters, per-wave ballot + LDS-atomic base ----
    const u64 below = (1ull << l) - 1ull;
#pragma unroll
    for (int e = 0; e < 16; ++e) {
        float v = bf2f((e < 8) ? c0[e] : c1[e - 8]);
        bool p = (v >= T);
        u64 mask = __ballot(p);
        int nw = (int)__popcll(mask);
        int base = 0;
        if (l == 0 && nw) base = atomicAdd(&cnt, nw);
        base = __shfl(base, 0);
        if (p) {
            int pos = base + (int)__popcll(mask & below);
            if (pos < CAP) cand[pos] = tid * 16 + e;
        }
    }
    __syncthreads();
    const int c = (cnt < CAP) ? cnt : CAP;    // >= KTH guaranteed

    // ---- 3. dots: candidate i -> wave i&3, lane i>>2 (exact seq-fmaf) ----
    {
        const int i = (l << 2) | w;
        if (i < c) {
            int n = cand[i];
            const float4* p1 = (const float4*)(nv1 + ((size_t)bt * NN + n) * DD);
            const float4* p2 = (const float4*)(nv2 + ((size_t)bt * NN + n) * DD);
            float acc = 0.f;
#pragma unroll
            for (int q = 0; q < 16; ++q) {
                float4 x = p1[q];
                acc = fmaf(embrow[q * 4 + 0], x.x, acc);
                acc = fmaf(embrow[q * 4 + 1], x.y, acc);
                acc = fmaf(embrow[q * 4 + 2], x.z, acc);
                acc = fmaf(embrow[q * 4 + 3], x.w, acc);
            }
#pragma unroll
            for (int q = 0; q < 16; ++q) {
                float4 x = p2[q];
                acc = fmaf(embrow[64 + q * 4 + 0], x.x, acc);
                acc = fmaf(embrow[64 + q * 4 + 1], x.y, acc);
                acc = fmaf(embrow[64 + q * 4 + 2], x.z, acc);
                acc = fmaf(embrow[64 + q * 4 + 3], x.w, acc);
            }
            keyL[i] = ((u64)ord32(acc) << 32) | (u64)(0xFFFFFFFFu - (unsigned)n);
        }
    }
    __syncthreads();

    // ---- 4. wave 0: sort 128 keys -> top-32 desc; write idx/b/t/widx ----
    const size_t obase = (size_t)row * TOPK;
    if (w == 0) {
        u64 A  = sort64_desc(keyL[l], l);
        u64 Bs = sort64_desc(keyL[64 + l], l);
        u64 rb = __shfl_xor(Bs, 63);
        u64 M  = A > rb ? A : rb;
#pragma unroll
        for (int j = 32; j >= 1; j >>= 1) {
            u64 o = __shfl_xor(M, j);
            M = ((l & j) == 0) ? (M > o ? M : o) : (M < o ? M : o);
        }
        const unsigned node = 0xFFFFFFFFu - (unsigned)(M & 0xFFFFFFFFull);
        if (l < TOPK) {
            const int b = bt / NT;
            out[IDX_OFF  + obase + l] = (float)node;
            out[BIDX_OFF + obase + l] = (float)b;
            out[TIDX_OFF + obase + l] = (float)(bt - b * NT);
            widx[l] = (int)node & (NN - 1);
        }
    }
    __syncthreads();

    // ---- 5. winner gather: 1024 chunk-tasks over 256 threads ----
#pragma unroll
    for (int it = 0; it < 4; ++it) {
        int id = it * 256 + tid;          // 0..1023
        int p  = id >> 5;                 // winner 0..31
        int ck = id & 31;                 // 32 chunks: 16 nv1 + 16 nv2
        int j  = ck & 15;
        bool h2 = ck >= 16;
        int n = widx[p];
        const float* basep = h2 ? nv2 : nv1;
        float4 sv = *(const float4*)(basep + ((size_t)bt * NN + n) * DD + j * 4);
        size_t o = (obase + p) * DD + j * 4;
        *(float4*)(out + (h2 ? SEL2_OFF : SEL1_OFF) + o) = sv;
    }
}

extern "C" void kernel_launch(void* const* d_in, const int* in_sizes, int n_in,
                              void* d_out, int out_size, void* d_ws, size_t ws_size,
                              hipStream_t stream) {
    const float* nv1 = (const float*)d_in[0];
    const float* nv2 = (const float*)d_in[1];
    const float* emb = (const float*)d_in[2];
    float* out = (float*)d_out;

    dim3 g1(32, BTc);
    k1_logits_bf16<<<g1, 256, 0, stream>>>(nv1, nv2, emb, (u16*)d_out);
    k2_fused<<<24576, 256, 0, stream>>>((const u16*)d_out, nv1, nv2, emb, out);
}